// Round 5
// baseline (2958.093 us; speedup 1.0000x reference)
//
#include <hip/hip_runtime.h>

typedef __bf16 bf16_t;
typedef __attribute__((ext_vector_type(8))) __bf16 bf16x8;
typedef __attribute__((ext_vector_type(4))) __bf16 bf16x4;
typedef __attribute__((ext_vector_type(4))) float f32x4;

// B=4, S=SM=1024, D=1024, H=16, HD=64, DFF=4096; M = B*S = 4096 rows.
// SETTLED (r4): external inputs fp32, d_out fp32 (x, sa_k, sa_v concat).
// Internals bf16 (MFMA), accumulate/residual fp32.
// ws: R0/R1/R2 = 3 x 8MB bf16 regions (24 MB total).

// fp32 -> bf16x8 loader (two float4 loads, RNE convert)
__device__ __forceinline__ bf16x8 load8f(const float* f) {
    float4 a = *(const float4*)f;
    float4 b = *(const float4*)(f + 4);
    bf16x8 r;
    r[0] = (bf16_t)a.x; r[1] = (bf16_t)a.y; r[2] = (bf16_t)a.z; r[3] = (bf16_t)a.w;
    r[4] = (bf16_t)b.x; r[5] = (bf16_t)b.y; r[6] = (bf16_t)b.z; r[7] = (bf16_t)b.w;
    return r;
}

// ---------------------------------------------------------------------------
// LayerNorm: one block per fp32 row of 1024 -> bf16 out (fp32 math).
// ---------------------------------------------------------------------------
__global__ __launch_bounds__(256) void ln_kernel(
    const float* __restrict__ x,
    const float* __restrict__ g, const float* __restrict__ be,
    bf16_t* __restrict__ out)
{
    int row = blockIdx.x, t = threadIdx.x;
    float4 q = *(const float4*)(x + (long)row * 1024 + t * 4);
    float v[4] = {q.x, q.y, q.z, q.w};
    float s = v[0] + v[1] + v[2] + v[3];
    float s2 = v[0]*v[0] + v[1]*v[1] + v[2]*v[2] + v[3]*v[3];
    for (int off = 32; off > 0; off >>= 1) {
        s  += __shfl_down(s, off);
        s2 += __shfl_down(s2, off);
    }
    __shared__ float rs[4], rq[4];
    int w = t >> 6;
    if ((t & 63) == 0) { rs[w] = s; rq[w] = s2; }
    __syncthreads();
    s  = rs[0] + rs[1] + rs[2] + rs[3];
    s2 = rq[0] + rq[1] + rq[2] + rq[3];
    float mean = s * (1.0f / 1024.0f);
    float var  = s2 * (1.0f / 1024.0f) - mean * mean;
    float rstd = rsqrtf(var + 1e-5f);
    int c = t * 4;
    for (int i = 0; i < 4; i++)
        out[(long)row * 1024 + c + i] =
            (bf16_t)((v[i] - mean) * rstd * g[c + i] + be[c + i]);
}

// ---------------------------------------------------------------------------
// NT GEMM: C[m,n] = sum_k A[m,k] * W[n,k]  (+bias, +relu, +fp32 residual)
// A: bf16 (row-major or head-layout [B,H,S,64] when a_head=1) or fp32
//    row-major external (a_f32=1). W: fp32 external row-major [N,K].
// 128x128 tile, BK=32, 4 waves (2x2), wave = 4x4 of 16x16x32 MFMA.
// Outputs (any subset): fp32 rm, bf16 rm, fp32 head, bf16 head.
// ---------------------------------------------------------------------------
#define LDT 40   // padded LDS row stride (32 data + 8 pad); rows 16B-aligned

__global__ __launch_bounds__(256) void gemm_nt(
    const void* __restrict__ A, int lda, int a_head, int a_f32,
    const float* __restrict__ W, long w_off, int ldw,
    int K,
    const float* __restrict__ bias, long b_off,  // fp32 or null
    const float* resid,                          // fp32 rm or null (may alias out_f32)
    float*  out_f32,                             // fp32 row-major or null
    bf16_t* __restrict__ out_b16,                // bf16 row-major or null
    float*  __restrict__ out_hf32,               // fp32 head layout or null
    bf16_t* __restrict__ out_hb16,               // bf16 head layout or null
    int N, int do_relu)
{
    __shared__ bf16_t As[128 * LDT];
    __shared__ bf16_t Bs[128 * LDT];
    int tid = threadIdx.x;
    int m0 = blockIdx.y << 7, n0 = blockIdx.x << 7;
    int wave = tid >> 6, lane = tid & 63;
    int wr = (wave >> 1) << 6;
    int wc = (wave & 1) << 6;
    int l15 = lane & 15, quad = lane >> 4;

    f32x4 acc[4][4];
    for (int i = 0; i < 4; i++)
        for (int j = 0; j < 4; j++)
            acc[i][j] = (f32x4){0.f, 0.f, 0.f, 0.f};

    int sr = tid >> 2;            // staging row 0..63 (and +64)
    int sc = (tid & 3) << 3;      // staging col {0,8,16,24}

    for (int k0 = 0; k0 < K; k0 += 32) {
        int kk = k0 + sc;
        long ia0, ia1;
        if (a_head) {
            int hh = kk >> 6, dd = kk & 63;
            int r0g = m0 + sr, r1g = r0g + 64;
            ia0 = ((((long)(r0g >> 10) * 16 + hh) * 1024 + (r0g & 1023)) << 6) + dd;
            ia1 = ((((long)(r1g >> 10) * 16 + hh) * 1024 + (r1g & 1023)) << 6) + dd;
        } else {
            ia0 = (long)(m0 + sr) * lda + kk;
            ia1 = (long)(m0 + sr + 64) * lda + kk;
        }
        long iw0 = w_off + (long)(n0 + sr) * ldw + kk;
        long iw1 = w_off + (long)(n0 + sr + 64) * ldw + kk;
        __syncthreads();
        if (a_f32) {
            *(bf16x8*)&As[sr * LDT + sc]        = load8f((const float*)A + ia0);
            *(bf16x8*)&As[(sr + 64) * LDT + sc] = load8f((const float*)A + ia1);
        } else {
            *(bf16x8*)&As[sr * LDT + sc]        = *(const bf16x8*)((const bf16_t*)A + ia0);
            *(bf16x8*)&As[(sr + 64) * LDT + sc] = *(const bf16x8*)((const bf16_t*)A + ia1);
        }
        *(bf16x8*)&Bs[sr * LDT + sc]        = load8f(W + iw0);
        *(bf16x8*)&Bs[(sr + 64) * LDT + sc] = load8f(W + iw1);
        __syncthreads();
        bf16x8 afr[4], bfr[4];
        for (int i = 0; i < 4; i++)
            afr[i] = *(const bf16x8*)&As[(wr + i * 16 + l15) * LDT + quad * 8];
        for (int j = 0; j < 4; j++)
            bfr[j] = *(const bf16x8*)&Bs[(wc + j * 16 + l15) * LDT + quad * 8];
        for (int i = 0; i < 4; i++)
            for (int j = 0; j < 4; j++)
                acc[i][j] = __builtin_amdgcn_mfma_f32_16x16x32_bf16(
                    afr[i], bfr[j], acc[i][j], 0, 0, 0);
    }

    int rb = quad << 2;  // C/D: col = lane&15, row = quad*4 + reg
    for (int i = 0; i < 4; i++) {
        for (int j = 0; j < 4; j++) {
            int col = n0 + wc + (j << 4) + l15;
            float bv = bias ? bias[b_off + col] : 0.0f;
            for (int r = 0; r < 4; r++) {
                int row = m0 + wr + (i << 4) + rb + r;
                float v = acc[i][j][r] + bv;
                if (do_relu) v = fmaxf(v, 0.0f);
                long idx = (long)row * N + col;
                if (resid) v += resid[idx];
                if (out_f32) out_f32[idx] = v;
                if (out_b16) out_b16[idx] = (bf16_t)v;
                if (out_hf32 || out_hb16) {
                    int bb = row >> 10, ss = row & 1023, hh = col >> 6, dd = col & 63;
                    long hidx = (((long)bb * 16 + hh) * 1024 + ss) * 64 + dd;
                    if (out_hf32) out_hf32[hidx] = v;
                    if (out_hb16) out_hb16[hidx] = (bf16_t)v;
                }
            }
        }
    }
}

// ---------------------------------------------------------------------------
// Flash attention (fp32 VALU, online softmax). Q bf16 head [B*H,S,64];
// K/V head layout, bf16 (internal) or fp32 (d_out) per kv_f32.
// Output bf16 written IN-PLACE over Q (block owns its 64x64 Q tile).
// ---------------------------------------------------------------------------
__global__ __launch_bounds__(256) void attn_kernel(
    const bf16_t* Q, const void* __restrict__ K,
    const void* __restrict__ V, bf16_t* AO,
    int Sk, int causal, int kv_f32)
{
    __shared__ float  Qs[64][68];
    __shared__ float  Ks[64][68];
    __shared__ float  Vs[64][68];
    __shared__ bf16_t Ps[64][72];
    int tid = threadIdx.x;
    int qt = blockIdx.x, bh = blockIdx.y;

    const bf16_t* Qb = Q + ((long)bh * 1024 + qt * 64) * 64;
    for (int c = tid; c < 512; c += 256) {
        int r = c >> 3, c8 = (c & 7) << 3;
        bf16x8 qv = *(const bf16x8*)&Qb[r * 64 + c8];
        for (int i = 0; i < 8; i++) Qs[r][c8 + i] = (float)qv[i] * 0.125f;  // 1/sqrt(64)
    }

    int r0 = (tid >> 4) << 2;      // 4 rows
    int c0 = (tid & 15) << 2;      // 4 cols
    float m_i[4] = {-1e30f, -1e30f, -1e30f, -1e30f};
    float l_i[4] = {0.f, 0.f, 0.f, 0.f};
    float o[4][4] = {};
    int nt = causal ? (qt + 1) : (Sk >> 6);
    long kvbase = (long)bh * Sk * 64;

    for (int kt = 0; kt < nt; kt++) {
        __syncthreads();   // prev PV done; Q staging visible on first iter
        int kbase = kt << 6;
        for (int c = tid; c < 512; c += 256) {
            int r = c >> 3, c8 = (c & 7) << 3;
            long off = kvbase + (long)(kbase + r) * 64 + c8;
            if (kv_f32) {
                const float* kp = (const float*)K + off;
                const float* vp = (const float*)V + off;
                float4 ka = *(const float4*)kp, kb = *(const float4*)(kp + 4);
                float4 va = *(const float4*)vp, vb = *(const float4*)(vp + 4);
                Ks[r][c8+0]=ka.x; Ks[r][c8+1]=ka.y; Ks[r][c8+2]=ka.z; Ks[r][c8+3]=ka.w;
                Ks[r][c8+4]=kb.x; Ks[r][c8+5]=kb.y; Ks[r][c8+6]=kb.z; Ks[r][c8+7]=kb.w;
                Vs[r][c8+0]=va.x; Vs[r][c8+1]=va.y; Vs[r][c8+2]=va.z; Vs[r][c8+3]=va.w;
                Vs[r][c8+4]=vb.x; Vs[r][c8+5]=vb.y; Vs[r][c8+6]=vb.z; Vs[r][c8+7]=vb.w;
            } else {
                bf16x8 kv = *(const bf16x8*)((const bf16_t*)K + off);
                bf16x8 vv = *(const bf16x8*)((const bf16_t*)V + off);
                for (int i = 0; i < 8; i++) {
                    Ks[r][c8 + i] = (float)kv[i];
                    Vs[r][c8 + i] = (float)vv[i];
                }
            }
        }
        __syncthreads();

        float s[4][4] = {};
        for (int d = 0; d < 64; d += 4) {
            float4 kc[4];
            for (int j = 0; j < 4; j++) kc[j] = *(const float4*)&Ks[c0 + j][d];
            for (int i = 0; i < 4; i++) {
                float4 qv = *(const float4*)&Qs[r0 + i][d];
                for (int j = 0; j < 4; j++)
                    s[i][j] += qv.x * kc[j].x + qv.y * kc[j].y +
                               qv.z * kc[j].z + qv.w * kc[j].w;
            }
        }
        if (causal) {
            int qrow = (qt << 6) + r0;
            for (int i = 0; i < 4; i++)
                for (int j = 0; j < 4; j++)
                    if (kbase + c0 + j > qrow + i) s[i][j] = -1e30f;
        }
        for (int i = 0; i < 4; i++) {
            float mx = fmaxf(fmaxf(s[i][0], s[i][1]), fmaxf(s[i][2], s[i][3]));
            for (int off = 1; off < 16; off <<= 1) mx = fmaxf(mx, __shfl_xor(mx, off));
            float mnew = fmaxf(m_i[i], mx);
            float alpha = __expf(m_i[i] - mnew);
            float p[4], rsum = 0.f;
            for (int j = 0; j < 4; j++) { p[j] = __expf(s[i][j] - mnew); rsum += p[j]; }
            for (int off = 1; off < 16; off <<= 1) rsum += __shfl_xor(rsum, off);
            l_i[i] = l_i[i] * alpha + rsum;
            m_i[i] = mnew;
            for (int j = 0; j < 4; j++) {
                o[i][j] *= alpha;
                Ps[r0 + i][c0 + j] = (bf16_t)p[j];
            }
        }
        __syncthreads();   // Ps visible
        for (int kk = 0; kk < 64; kk += 4) {
            bf16x4 pr[4];
            for (int i = 0; i < 4; i++) pr[i] = *(const bf16x4*)&Ps[r0 + i][kk];
            for (int x = 0; x < 4; x++) {
                float4 vv = *(const float4*)&Vs[kk + x][c0];
                for (int i = 0; i < 4; i++) {
                    float pv = (float)pr[i][x];
                    o[i][0] += pv * vv.x; o[i][1] += pv * vv.y;
                    o[i][2] += pv * vv.z; o[i][3] += pv * vv.w;
                }
            }
        }
    }

    bf16_t* Ob = AO + ((long)bh * 1024 + qt * 64) * 64;
    for (int i = 0; i < 4; i++) {
        float inv = 1.0f / l_i[i];
        for (int j = 0; j < 4; j++)
            Ob[(r0 + i) * 64 + c0 + j] = (bf16_t)(o[i][j] * inv);
    }
}

// ---------------------------------------------------------------------------
extern "C" void kernel_launch(void* const* d_in, const int* in_sizes, int n_in,
                              void* d_out, int out_size, void* d_ws, size_t ws_size,
                              hipStream_t stream)
{
    (void)in_sizes; (void)n_in; (void)out_size; (void)ws_size;
    const float* tgt       = (const float*)d_in[0];
    const float* mem       = (const float*)d_in[1];
    const float* Wq        = (const float*)d_in[2];
    const float* Wk        = (const float*)d_in[3];
    const float* Wv        = (const float*)d_in[4];
    const float* Wo        = (const float*)d_in[5];
    const float* mha_in_w  = (const float*)d_in[6];
    const float* mha_in_b  = (const float*)d_in[7];
    const float* mha_out_w = (const float*)d_in[8];
    const float* mha_out_b = (const float*)d_in[9];
    const float* W1        = (const float*)d_in[10];
    const float* b1        = (const float*)d_in[11];
    const float* W2        = (const float*)d_in[12];
    const float* b2        = (const float*)d_in[13];
    const float* g1        = (const float*)d_in[14];
    const float* be1       = (const float*)d_in[15];
    const float* g2        = (const float*)d_in[16];
    const float* be2       = (const float*)d_in[17];
    const float* g3        = (const float*)d_in[18];
    const float* be3       = (const float*)d_in[19];

    float* out_x = (float*)d_out;                 // x [B,S,D] fp32 (holds residual mid-flight)
    float* out_k = out_x + (1 << 22);             // sa_k [B,H,S,64] fp32
    float* out_v = out_k + (1 << 22);             // sa_v fp32

    bf16_t* R0 = (bf16_t*)d_ws;                   // LN out / cross-V head
    bf16_t* R1 = R0 + (1 << 22);                  // Qh (attn out in-place) / FFN hidden lo
    bf16_t* R2 = R1 + (1 << 22);                  // cross-K head / FFN hidden hi

    dim3 blk(256);
    dim3 gD(8, 32);     // N=1024, M=4096
    dim3 gA(16, 64);    // attention: (q-tiles, B*H)
    dim3 gF1(32, 16);   // N=4096, M=2048 (FFN chunk, gemm1)
    dim3 gF2(8, 16);    // N=1024, M=2048 (FFN chunk, gemm2)

    // ---- self-attention ----
    ln_kernel<<<4096, blk, 0, stream>>>(tgt, g1, be1, R0);
    gemm_nt<<<gD, blk, 0, stream>>>(R0, 1024, 0, 0, Wq, 0, 1024, 1024,
                                    nullptr, 0, nullptr, nullptr, nullptr,
                                    nullptr, R1, 1024, 0);
    gemm_nt<<<gD, blk, 0, stream>>>(R0, 1024, 0, 0, Wk, 0, 1024, 1024,
                                    nullptr, 0, nullptr, nullptr, nullptr,
                                    out_k, nullptr, 1024, 0);
    gemm_nt<<<gD, blk, 0, stream>>>(R0, 1024, 0, 0, Wv, 0, 1024, 1024,
                                    nullptr, 0, nullptr, nullptr, nullptr,
                                    out_v, nullptr, 1024, 0);
    attn_kernel<<<gA, blk, 0, stream>>>(R1, out_k, out_v, R1, 1024, 1, 1);
    gemm_nt<<<gD, blk, 0, stream>>>(R1, 0, 1, 0, Wo, 0, 1024, 1024,
                                    nullptr, 0, tgt, out_x, nullptr,
                                    nullptr, nullptr, 1024, 0);

    // ---- cross-attention ----
    ln_kernel<<<4096, blk, 0, stream>>>(out_x, g2, be2, R0);
    gemm_nt<<<gD, blk, 0, stream>>>(R0, 1024, 0, 0, mha_in_w, 0, 1024, 1024,
                                    mha_in_b, 0, nullptr, nullptr, nullptr,
                                    nullptr, R1, 1024, 0);
    gemm_nt<<<gD, blk, 0, stream>>>(mem, 1024, 0, 1, mha_in_w, (long)1 << 20, 1024, 1024,
                                    mha_in_b, 1024, nullptr, nullptr, nullptr,
                                    nullptr, R2, 1024, 0);
    gemm_nt<<<gD, blk, 0, stream>>>(mem, 1024, 0, 1, mha_in_w, (long)2 << 20, 1024, 1024,
                                    mha_in_b, 2048, nullptr, nullptr, nullptr,
                                    nullptr, R0, 1024, 0);
    attn_kernel<<<gA, blk, 0, stream>>>(R1, R2, R0, R1, 1024, 0, 0);
    gemm_nt<<<gD, blk, 0, stream>>>(R1, 0, 1, 0, mha_out_w, 0, 1024, 1024,
                                    mha_out_b, 0, out_x, out_x, nullptr,
                                    nullptr, nullptr, 1024, 0);

    // ---- FFN (2 chunks of 2048 rows; hidden bf16 16MB spans R1+R2) ----
    ln_kernel<<<4096, blk, 0, stream>>>(out_x, g3, be3, R0);
    for (int c = 0; c < 2; c++) {
        const bf16_t* Ac = R0 + (long)c * 2048 * 1024;
        bf16_t*       Hc = R1;                        // 2048x4096 bf16 = 16MB
        float*        Xc = out_x + (long)c * 2048 * 1024;
        gemm_nt<<<gF1, blk, 0, stream>>>(Ac, 1024, 0, 0, W1, 0, 1024, 1024,
                                         b1, 0, nullptr, nullptr, Hc,
                                         nullptr, nullptr, 4096, 1);
        gemm_nt<<<gF2, blk, 0, stream>>>(Hc, 4096, 0, 0, W2, 0, 4096, 4096,
                                         b2, 0, Xc, Xc, nullptr,
                                         nullptr, nullptr, 1024, 0);
    }
}

// Round 6
// 2312.959 us; speedup vs baseline: 1.2789x; 1.2789x over previous
//
#include <hip/hip_runtime.h>

typedef __bf16 bf16_t;
typedef unsigned int u32;
typedef __attribute__((ext_vector_type(8))) __bf16 bf16x8;
typedef __attribute__((ext_vector_type(4))) __bf16 bf16x4;
typedef __attribute__((ext_vector_type(4))) float f32x4;

// B=4, S=SM=1024, D=1024, H=16, HD=64, DFF=4096; M = B*S = 4096 rows.
// Inputs fp32; d_out fp32 (x, sa_k, sa_v). Internals bf16 (MFMA).
//
// FAST PATH (ws_size >= 96MB):
//   R0/R1/R2 bf16 [0,8)/[8,16)/[16,24) MB, Hff [24,56), Wb bf16 [56,88),
//   memb bf16 [88,96). Weights+mem pre-converted to bf16 once; GEMMs use
//   global_load_lds(16B) m97-style K-loop; QKV and cross-KV fused.
// FALLBACK (small ws): round-5 path (24MB), known passing.

__device__ __forceinline__ bf16x8 load8f(const float* f) {
    float4 a = *(const float4*)f;
    float4 b = *(const float4*)(f + 4);
    bf16x8 r;
    r[0] = (bf16_t)a.x; r[1] = (bf16_t)a.y; r[2] = (bf16_t)a.z; r[3] = (bf16_t)a.w;
    r[4] = (bf16_t)b.x; r[5] = (bf16_t)b.y; r[6] = (bf16_t)b.z; r[7] = (bf16_t)b.w;
    return r;
}

// async 16B/lane global->LDS (CK cast idiom; LDS dest wave-uniform base + lane*16)
__device__ __forceinline__ void gll16(const void* g, const void* l) {
    __builtin_amdgcn_global_load_lds(
        (const __attribute__((address_space(1))) u32*)(unsigned long long)g,
        (__attribute__((address_space(3))) u32*)(unsigned int)(unsigned long long)l,
        16, 0, 0);
}

// ---------------------------------------------------------------------------
// Convert fp32 weights (+memory) into one contiguous bf16 buffer.
// Segment map (elem offsets in dst):
//   [0,1M) Wq | [1M,2M) Wk | [2M,3M) Wv | [3M,4M) Wo | [4M,7M) mha_in_w |
//   [7M,8M) mha_out_w | [8M,12M) W1 | [12M,16M) W2 | [16M,20M) mem
// ---------------------------------------------------------------------------
__global__ __launch_bounds__(256) void conv_kernel(
    const float* __restrict__ Wq, const float* __restrict__ Wk,
    const float* __restrict__ Wv, const float* __restrict__ Wo,
    const float* __restrict__ Wio, const float* __restrict__ Woo,
    const float* __restrict__ W1, const float* __restrict__ W2,
    const float* __restrict__ mem, bf16_t* __restrict__ dst)
{
    long e = ((long)blockIdx.x * 256 + threadIdx.x) * 8;
    const float* s; long o;
    if      (e <  1048576) { s = Wq;  o = e; }
    else if (e <  2097152) { s = Wk;  o = e -  1048576; }
    else if (e <  3145728) { s = Wv;  o = e -  2097152; }
    else if (e <  4194304) { s = Wo;  o = e -  3145728; }
    else if (e <  7340032) { s = Wio; o = e -  4194304; }
    else if (e <  8388608) { s = Woo; o = e -  7340032; }
    else if (e < 12582912) { s = W1;  o = e -  8388608; }
    else if (e < 16777216) { s = W2;  o = e - 12582912; }
    else                   { s = mem; o = e - 16777216; }
    *(bf16x8*)&dst[e] = load8f(s + o);
}

// ---------------------------------------------------------------------------
// LayerNorm: one block per fp32 row of 1024 -> bf16 out (fp32 math).
// ---------------------------------------------------------------------------
__global__ __launch_bounds__(256) void ln_kernel(
    const float* __restrict__ x,
    const float* __restrict__ g, const float* __restrict__ be,
    bf16_t* __restrict__ out)
{
    int row = blockIdx.x, t = threadIdx.x;
    float4 q = *(const float4*)(x + (long)row * 1024 + t * 4);
    float v[4] = {q.x, q.y, q.z, q.w};
    float s = v[0] + v[1] + v[2] + v[3];
    float s2 = v[0]*v[0] + v[1]*v[1] + v[2]*v[2] + v[3]*v[3];
    for (int off = 32; off > 0; off >>= 1) {
        s  += __shfl_down(s, off);
        s2 += __shfl_down(s2, off);
    }
    __shared__ float rs[4], rq[4];
    int w = t >> 6;
    if ((t & 63) == 0) { rs[w] = s; rq[w] = s2; }
    __syncthreads();
    s  = rs[0] + rs[1] + rs[2] + rs[3];
    s2 = rq[0] + rq[1] + rq[2] + rq[3];
    float mean = s * (1.0f / 1024.0f);
    float var  = s2 * (1.0f / 1024.0f) - mean * mean;
    float rstd = rsqrtf(var + 1e-5f);
    int c = t * 4;
    for (int i = 0; i < 4; i++)
        out[(long)row * 1024 + c + i] =
            (bf16_t)((v[i] - mean) * rstd * g[c + i] + be[c + i]);
}

// ---------------------------------------------------------------------------
// FAST NT GEMM (all-bf16 operands): C = A * W^T (+bias,+relu,+fp32 resid)
// 128x128 tile, BK=32, global_load_lds(16B) staging, unpadded LDS [row][32].
// A: bf16 rm (lda) or head-layout [B,H,S,64] (a_head).  W: bf16 rm [N][K].
// mode 0: o0=f32 rm | o1=b16 rm | o2=b16 head (any subset)
// mode 1 (QKV):     col seg0 -> o0 b16 head, seg1 -> o1 f32 head, seg2 -> o2 f32 head
// mode 2 (crossKV): col seg0 -> o0 b16 head, seg1 -> o1 b16 head
// ---------------------------------------------------------------------------
__global__ __launch_bounds__(256) void gemm_fast(
    const bf16_t* __restrict__ A, int lda, int a_head,
    const bf16_t* __restrict__ Wb, long w_off, int ldw, int K,
    const float* __restrict__ bias, long b_off,
    const float* resid,
    void* o0, void* o1, void* o2, int mode, int N, int do_relu)
{
    __shared__ __align__(16) bf16_t As[128 * 32];
    __shared__ __align__(16) bf16_t Bs[128 * 32];
    int tid = threadIdx.x;
    int m0 = blockIdx.y << 7, n0 = blockIdx.x << 7;
    int w = tid >> 6, lane = tid & 63;
    int l15 = lane & 15, quad = lane >> 4;
    int wr = (w >> 1) << 6, wc = (w & 1) << 6;

    // staging geometry: per wave 2 instrs of 16 rows each; lane -> row/chunk
    int sr0 = w * 32 + (lane >> 2);     // rows w*32 .. w*32+15
    int sck = (lane & 3) << 3;          // k-chunk {0,8,16,24}
    const bf16_t* lA0 = &As[(w * 32) * 32];
    const bf16_t* lA1 = &As[(w * 32 + 16) * 32];
    const bf16_t* lB0 = &Bs[(w * 32) * 32];
    const bf16_t* lB1 = &Bs[(w * 32 + 16) * 32];

    f32x4 acc[4][4];
    for (int i = 0; i < 4; i++)
        for (int j = 0; j < 4; j++)
            acc[i][j] = (f32x4){0.f, 0.f, 0.f, 0.f};

    const bf16_t* Wg = Wb + w_off;
    for (int k0 = 0; k0 < K; k0 += 32) {
        int kk = k0 + sck;
        const bf16_t *ga0, *ga1;
        if (a_head) {
            int hh = kk >> 6, dd = kk & 63;
            int r0g = m0 + sr0, r1g = r0g + 16;
            ga0 = A + ((((long)(r0g >> 10) * 16 + hh) * 1024 + (r0g & 1023)) << 6) + dd;
            ga1 = A + ((((long)(r1g >> 10) * 16 + hh) * 1024 + (r1g & 1023)) << 6) + dd;
        } else {
            ga0 = A + (long)(m0 + sr0) * lda + kk;
            ga1 = ga0 + (long)16 * lda;
        }
        const bf16_t* gb0 = Wg + (long)(n0 + sr0) * ldw + kk;
        const bf16_t* gb1 = gb0 + (long)16 * ldw;
        __syncthreads();                    // all frag reads of prev tile done
        gll16(ga0, lA0);
        gll16(ga1, lA1);
        gll16(gb0, lB0);
        gll16(gb1, lB1);
        __syncthreads();                    // vmcnt(0) drained before barrier
        bf16x8 af[4], bf_[4];
        for (int i = 0; i < 4; i++)
            af[i]  = *(const bf16x8*)&As[(wr + i * 16 + l15) * 32 + quad * 8];
        for (int j = 0; j < 4; j++)
            bf_[j] = *(const bf16x8*)&Bs[(wc + j * 16 + l15) * 32 + quad * 8];
        for (int i = 0; i < 4; i++)
            for (int j = 0; j < 4; j++)
                acc[i][j] = __builtin_amdgcn_mfma_f32_16x16x32_bf16(
                    af[i], bf_[j], acc[i][j], 0, 0, 0);
    }

    int rb = quad << 2;  // C/D: col = lane&15, row = quad*4 + reg
    for (int i = 0; i < 4; i++) {
        for (int j = 0; j < 4; j++) {
            int col = n0 + wc + (j << 4) + l15;
            float bv = bias ? bias[b_off + col] : 0.0f;
            for (int r = 0; r < 4; r++) {
                int row = m0 + wr + (i << 4) + rb + r;
                float v = acc[i][j][r] + bv;
                if (do_relu) v = fmaxf(v, 0.0f);
                if (mode == 0) {
                    long idx = (long)row * N + col;
                    if (resid) v += resid[idx];
                    if (o0) ((float*)o0)[idx] = v;
                    if (o1) ((bf16_t*)o1)[idx] = (bf16_t)v;
                    if (o2) {
                        long hidx = (((long)(row >> 10) * 16 + (col >> 6)) * 1024
                                     + (row & 1023)) * 64 + (col & 63);
                        ((bf16_t*)o2)[hidx] = (bf16_t)v;
                    }
                } else {
                    int seg = col >> 10, c = col & 1023;
                    long hidx = (((long)(row >> 10) * 16 + (c >> 6)) * 1024
                                 + (row & 1023)) * 64 + (c & 63);
                    if (mode == 1) {
                        if (seg == 0)      ((bf16_t*)o0)[hidx] = (bf16_t)v;
                        else if (seg == 1) ((float*)o1)[hidx] = v;
                        else               ((float*)o2)[hidx] = v;
                    } else {
                        if (seg == 0)      ((bf16_t*)o0)[hidx] = (bf16_t)v;
                        else               ((bf16_t*)o1)[hidx] = (bf16_t)v;
                    }
                }
            }
        }
    }
}

// ---------------------------------------------------------------------------
// FALLBACK NT GEMM (round-5, fp32 weights) — used only when ws is small.
// ---------------------------------------------------------------------------
#define LDT 40

__global__ __launch_bounds__(256) void gemm_nt(
    const void* __restrict__ A, int lda, int a_head, int a_f32,
    const float* __restrict__ W, long w_off, int ldw,
    int K,
    const float* __restrict__ bias, long b_off,
    const float* resid,
    float*  out_f32, bf16_t* __restrict__ out_b16,
    float*  __restrict__ out_hf32, bf16_t* __restrict__ out_hb16,
    int N, int do_relu)
{
    __shared__ bf16_t As[128 * LDT];
    __shared__ bf16_t Bs[128 * LDT];
    int tid = threadIdx.x;
    int m0 = blockIdx.y << 7, n0 = blockIdx.x << 7;
    int wave = tid >> 6, lane = tid & 63;
    int wr = (wave >> 1) << 6;
    int wc = (wave & 1) << 6;
    int l15 = lane & 15, quad = lane >> 4;

    f32x4 acc[4][4];
    for (int i = 0; i < 4; i++)
        for (int j = 0; j < 4; j++)
            acc[i][j] = (f32x4){0.f, 0.f, 0.f, 0.f};

    int sr = tid >> 2;
    int sc = (tid & 3) << 3;

    for (int k0 = 0; k0 < K; k0 += 32) {
        int kk = k0 + sc;
        long ia0, ia1;
        if (a_head) {
            int hh = kk >> 6, dd = kk & 63;
            int r0g = m0 + sr, r1g = r0g + 64;
            ia0 = ((((long)(r0g >> 10) * 16 + hh) * 1024 + (r0g & 1023)) << 6) + dd;
            ia1 = ((((long)(r1g >> 10) * 16 + hh) * 1024 + (r1g & 1023)) << 6) + dd;
        } else {
            ia0 = (long)(m0 + sr) * lda + kk;
            ia1 = (long)(m0 + sr + 64) * lda + kk;
        }
        long iw0 = w_off + (long)(n0 + sr) * ldw + kk;
        long iw1 = w_off + (long)(n0 + sr + 64) * ldw + kk;
        __syncthreads();
        if (a_f32) {
            *(bf16x8*)&As[sr * LDT + sc]        = load8f((const float*)A + ia0);
            *(bf16x8*)&As[(sr + 64) * LDT + sc] = load8f((const float*)A + ia1);
        } else {
            *(bf16x8*)&As[sr * LDT + sc]        = *(const bf16x8*)((const bf16_t*)A + ia0);
            *(bf16x8*)&As[(sr + 64) * LDT + sc] = *(const bf16x8*)((const bf16_t*)A + ia1);
        }
        *(bf16x8*)&Bs[sr * LDT + sc]        = load8f(W + iw0);
        *(bf16x8*)&Bs[(sr + 64) * LDT + sc] = load8f(W + iw1);
        __syncthreads();
        bf16x8 afr[4], bfr[4];
        for (int i = 0; i < 4; i++)
            afr[i] = *(const bf16x8*)&As[(wr + i * 16 + l15) * LDT + quad * 8];
        for (int j = 0; j < 4; j++)
            bfr[j] = *(const bf16x8*)&Bs[(wc + j * 16 + l15) * LDT + quad * 8];
        for (int i = 0; i < 4; i++)
            for (int j = 0; j < 4; j++)
                acc[i][j] = __builtin_amdgcn_mfma_f32_16x16x32_bf16(
                    afr[i], bfr[j], acc[i][j], 0, 0, 0);
    }

    int rb = quad << 2;
    for (int i = 0; i < 4; i++) {
        for (int j = 0; j < 4; j++) {
            int col = n0 + wc + (j << 4) + l15;
            float bv = bias ? bias[b_off + col] : 0.0f;
            for (int r = 0; r < 4; r++) {
                int row = m0 + wr + (i << 4) + rb + r;
                float v = acc[i][j][r] + bv;
                if (do_relu) v = fmaxf(v, 0.0f);
                long idx = (long)row * N + col;
                if (resid) v += resid[idx];
                if (out_f32) out_f32[idx] = v;
                if (out_b16) out_b16[idx] = (bf16_t)v;
                if (out_hf32 || out_hb16) {
                    int bb = row >> 10, ss = row & 1023, hh = col >> 6, dd = col & 63;
                    long hidx = (((long)bb * 16 + hh) * 1024 + ss) * 64 + dd;
                    if (out_hf32) out_hf32[hidx] = v;
                    if (out_hb16) out_hb16[hidx] = (bf16_t)v;
                }
            }
        }
    }
}

// ---------------------------------------------------------------------------
// Flash attention (fp32 VALU, online softmax). Q bf16 head [B*H,S,64];
// K/V head layout, bf16 or fp32 per kv_f32. Output bf16 in-place over Q.
// ---------------------------------------------------------------------------
__global__ __launch_bounds__(256) void attn_kernel(
    const bf16_t* Q, const void* __restrict__ K,
    const void* __restrict__ V, bf16_t* AO,
    int Sk, int causal, int kv_f32)
{
    __shared__ float  Qs[64][68];
    __shared__ float  Ks[64][68];
    __shared__ float  Vs[64][68];
    __shared__ bf16_t Ps[64][72];
    int tid = threadIdx.x;
    int qt = blockIdx.x, bh = blockIdx.y;

    const bf16_t* Qb = Q + ((long)bh * 1024 + qt * 64) * 64;
    for (int c = tid; c < 512; c += 256) {
        int r = c >> 3, c8 = (c & 7) << 3;
        bf16x8 qv = *(const bf16x8*)&Qb[r * 64 + c8];
        for (int i = 0; i < 8; i++) Qs[r][c8 + i] = (float)qv[i] * 0.125f;
    }

    int r0 = (tid >> 4) << 2;
    int c0 = (tid & 15) << 2;
    float m_i[4] = {-1e30f, -1e30f, -1e30f, -1e30f};
    float l_i[4] = {0.f, 0.f, 0.f, 0.f};
    float o[4][4] = {};
    int nt = causal ? (qt + 1) : (Sk >> 6);
    long kvbase = (long)bh * Sk * 64;

    for (int kt = 0; kt < nt; kt++) {
        __syncthreads();
        int kbase = kt << 6;
        for (int c = tid; c < 512; c += 256) {
            int r = c >> 3, c8 = (c & 7) << 3;
            long off = kvbase + (long)(kbase + r) * 64 + c8;
            if (kv_f32) {
                const float* kp = (const float*)K + off;
                const float* vp = (const float*)V + off;
                float4 ka = *(const float4*)kp, kb = *(const float4*)(kp + 4);
                float4 va = *(const float4*)vp, vb = *(const float4*)(vp + 4);
                Ks[r][c8+0]=ka.x; Ks[r][c8+1]=ka.y; Ks[r][c8+2]=ka.z; Ks[r][c8+3]=ka.w;
                Ks[r][c8+4]=kb.x; Ks[r][c8+5]=kb.y; Ks[r][c8+6]=kb.z; Ks[r][c8+7]=kb.w;
                Vs[r][c8+0]=va.x; Vs[r][c8+1]=va.y; Vs[r][c8+2]=va.z; Vs[r][c8+3]=va.w;
                Vs[r][c8+4]=vb.x; Vs[r][c8+5]=vb.y; Vs[r][c8+6]=vb.z; Vs[r][c8+7]=vb.w;
            } else {
                bf16x8 kv = *(const bf16x8*)((const bf16_t*)K + off);
                bf16x8 vv = *(const bf16x8*)((const bf16_t*)V + off);
                for (int i = 0; i < 8; i++) {
                    Ks[r][c8 + i] = (float)kv[i];
                    Vs[r][c8 + i] = (float)vv[i];
                }
            }
        }
        __syncthreads();

        float s[4][4] = {};
        for (int d = 0; d < 64; d += 4) {
            float4 kc[4];
            for (int j = 0; j < 4; j++) kc[j] = *(const float4*)&Ks[c0 + j][d];
            for (int i = 0; i < 4; i++) {
                float4 qv = *(const float4*)&Qs[r0 + i][d];
                for (int j = 0; j < 4; j++)
                    s[i][j] += qv.x * kc[j].x + qv.y * kc[j].y +
                               qv.z * kc[j].z + qv.w * kc[j].w;
            }
        }
        if (causal) {
            int qrow = (qt << 6) + r0;
            for (int i = 0; i < 4; i++)
                for (int j = 0; j < 4; j++)
                    if (kbase + c0 + j > qrow + i) s[i][j] = -1e30f;
        }
        for (int i = 0; i < 4; i++) {
            float mx = fmaxf(fmaxf(s[i][0], s[i][1]), fmaxf(s[i][2], s[i][3]));
            for (int off = 1; off < 16; off <<= 1) mx = fmaxf(mx, __shfl_xor(mx, off));
            float mnew = fmaxf(m_i[i], mx);
            float alpha = __expf(m_i[i] - mnew);
            float p[4], rsum = 0.f;
            for (int j = 0; j < 4; j++) { p[j] = __expf(s[i][j] - mnew); rsum += p[j]; }
            for (int off = 1; off < 16; off <<= 1) rsum += __shfl_xor(rsum, off);
            l_i[i] = l_i[i] * alpha + rsum;
            m_i[i] = mnew;
            for (int j = 0; j < 4; j++) {
                o[i][j] *= alpha;
                Ps[r0 + i][c0 + j] = (bf16_t)p[j];
            }
        }
        __syncthreads();
        for (int kk = 0; kk < 64; kk += 4) {
            bf16x4 pr[4];
            for (int i = 0; i < 4; i++) pr[i] = *(const bf16x4*)&Ps[r0 + i][kk];
            for (int x = 0; x < 4; x++) {
                float4 vv = *(const float4*)&Vs[kk + x][c0];
                for (int i = 0; i < 4; i++) {
                    float pv = (float)pr[i][x];
                    o[i][0] += pv * vv.x; o[i][1] += pv * vv.y;
                    o[i][2] += pv * vv.z; o[i][3] += pv * vv.w;
                }
            }
        }
    }

    bf16_t* Ob = AO + ((long)bh * 1024 + qt * 64) * 64;
    for (int i = 0; i < 4; i++) {
        float inv = 1.0f / l_i[i];
        for (int j = 0; j < 4; j++)
            Ob[(r0 + i) * 64 + c0 + j] = (bf16_t)(o[i][j] * inv);
    }
}

// ---------------------------------------------------------------------------
extern "C" void kernel_launch(void* const* d_in, const int* in_sizes, int n_in,
                              void* d_out, int out_size, void* d_ws, size_t ws_size,
                              hipStream_t stream)
{
    (void)in_sizes; (void)n_in; (void)out_size;
    const float* tgt       = (const float*)d_in[0];
    const float* mem       = (const float*)d_in[1];
    const float* Wq        = (const float*)d_in[2];
    const float* Wk        = (const float*)d_in[3];
    const float* Wv        = (const float*)d_in[4];
    const float* Wo        = (const float*)d_in[5];
    const float* mha_in_w  = (const float*)d_in[6];
    const float* mha_in_b  = (const float*)d_in[7];
    const float* mha_out_w = (const float*)d_in[8];
    const float* mha_out_b = (const float*)d_in[9];
    const float* W1        = (const float*)d_in[10];
    const float* b1        = (const float*)d_in[11];
    const float* W2        = (const float*)d_in[12];
    const float* b2        = (const float*)d_in[13];
    const float* g1        = (const float*)d_in[14];
    const float* be1       = (const float*)d_in[15];
    const float* g2        = (const float*)d_in[16];
    const float* be2       = (const float*)d_in[17];
    const float* g3        = (const float*)d_in[18];
    const float* be3       = (const float*)d_in[19];

    float* out_x = (float*)d_out;
    float* out_k = out_x + (1 << 22);
    float* out_v = out_k + (1 << 22);

    bf16_t* R0 = (bf16_t*)d_ws;
    bf16_t* R1 = R0 + (1 << 22);
    bf16_t* R2 = R1 + (1 << 22);

    dim3 blk(256);
    dim3 gA(16, 64);

    if (ws_size >= ((size_t)96 << 20)) {
        // ---------------- FAST PATH ----------------
        bf16_t* Hff  = R2 + (1 << 22);                            // [24,56) MB
        bf16_t* Wb   = (bf16_t*)((char*)d_ws + ((size_t)56 << 20)); // [56,88)
        bf16_t* memb = Wb + 16777216;                             // [88,96)
        const long WO_OFF  = 3145728;
        const long CQ_OFF  = 4194304;
        const long CKV_OFF = 5242880;
        const long CO_OFF  = 7340032;
        const long W1_OFF  = 8388608;
        const long W2_OFF  = 12582912;

        conv_kernel<<<10240, blk, 0, stream>>>(Wq, Wk, Wv, Wo, mha_in_w,
                                               mha_out_w, W1, W2, mem, Wb);

        // ---- self-attention ----
        ln_kernel<<<4096, blk, 0, stream>>>(tgt, g1, be1, R0);
        gemm_fast<<<dim3(24, 32), blk, 0, stream>>>(R0, 1024, 0, Wb, 0, 1024, 1024,
                                                    nullptr, 0, nullptr,
                                                    R1, out_k, out_v, 1, 3072, 0);
        attn_kernel<<<gA, blk, 0, stream>>>(R1, out_k, out_v, R1, 1024, 1, 1);
        gemm_fast<<<dim3(8, 32), blk, 0, stream>>>(R1, 0, 1, Wb, WO_OFF, 1024, 1024,
                                                   nullptr, 0, tgt,
                                                   out_x, nullptr, nullptr, 0, 1024, 0);

        // ---- cross-attention ----
        ln_kernel<<<4096, blk, 0, stream>>>(out_x, g2, be2, R0);
        gemm_fast<<<dim3(8, 32), blk, 0, stream>>>(R0, 1024, 0, Wb, CQ_OFF, 1024, 1024,
                                                   mha_in_b, 0, nullptr,
                                                   nullptr, nullptr, R1, 0, 1024, 0);
        gemm_fast<<<dim3(16, 32), blk, 0, stream>>>(memb, 1024, 0, Wb, CKV_OFF, 1024, 1024,
                                                    mha_in_b, 1024, nullptr,
                                                    R2, R0, nullptr, 2, 2048, 0);
        attn_kernel<<<gA, blk, 0, stream>>>(R1, R2, R0, R1, 1024, 0, 0);
        gemm_fast<<<dim3(8, 32), blk, 0, stream>>>(R1, 0, 1, Wb, CO_OFF, 1024, 1024,
                                                   mha_out_b, 0, out_x,
                                                   out_x, nullptr, nullptr, 0, 1024, 0);

        // ---- FFN (full M) ----
        ln_kernel<<<4096, blk, 0, stream>>>(out_x, g3, be3, R0);
        gemm_fast<<<dim3(32, 32), blk, 0, stream>>>(R0, 1024, 0, Wb, W1_OFF, 1024, 1024,
                                                    b1, 0, nullptr,
                                                    nullptr, Hff, nullptr, 0, 4096, 1);
        gemm_fast<<<dim3(8, 32), blk, 0, stream>>>(Hff, 4096, 0, Wb, W2_OFF, 4096, 4096,
                                                   b2, 0, out_x,
                                                   out_x, nullptr, nullptr, 0, 1024, 0);
        return;
    }

    // ---------------- FALLBACK (round-5, known passing) ----------------
    dim3 gD(8, 32);
    dim3 gF1(32, 16);
    dim3 gF2(8, 16);

    ln_kernel<<<4096, blk, 0, stream>>>(tgt, g1, be1, R0);
    gemm_nt<<<gD, blk, 0, stream>>>(R0, 1024, 0, 0, Wq, 0, 1024, 1024,
                                    nullptr, 0, nullptr, nullptr, nullptr,
                                    nullptr, R1, 1024, 0);
    gemm_nt<<<gD, blk, 0, stream>>>(R0, 1024, 0, 0, Wk, 0, 1024, 1024,
                                    nullptr, 0, nullptr, nullptr, nullptr,
                                    out_k, nullptr, 1024, 0);
    gemm_nt<<<gD, blk, 0, stream>>>(R0, 1024, 0, 0, Wv, 0, 1024, 1024,
                                    nullptr, 0, nullptr, nullptr, nullptr,
                                    out_v, nullptr, 1024, 0);
    attn_kernel<<<gA, blk, 0, stream>>>(R1, out_k, out_v, R1, 1024, 1, 1);
    gemm_nt<<<gD, blk, 0, stream>>>(R1, 0, 1, 0, Wo, 0, 1024, 1024,
                                    nullptr, 0, tgt, out_x, nullptr,
                                    nullptr, nullptr, 1024, 0);

    ln_kernel<<<4096, blk, 0, stream>>>(out_x, g2, be2, R0);
    gemm_nt<<<gD, blk, 0, stream>>>(R0, 1024, 0, 0, mha_in_w, 0, 1024, 1024,
                                    mha_in_b, 0, nullptr, nullptr, nullptr,
                                    nullptr, R1, 1024, 0);
    gemm_nt<<<gD, blk, 0, stream>>>(mem, 1024, 0, 1, mha_in_w, (long)1 << 20, 1024, 1024,
                                    mha_in_b, 1024, nullptr, nullptr, nullptr,
                                    nullptr, R2, 1024, 0);
    gemm_nt<<<gD, blk, 0, stream>>>(mem, 1024, 0, 1, mha_in_w, (long)2 << 20, 1024, 1024,
                                    mha_in_b, 2048, nullptr, nullptr, nullptr,
                                    nullptr, R0, 1024, 0);
    attn_kernel<<<gA, blk, 0, stream>>>(R1, R2, R0, R1, 1024, 0, 0);
    gemm_nt<<<gD, blk, 0, stream>>>(R1, 0, 1, 0, mha_out_w, 0, 1024, 1024,
                                    mha_out_b, 0, out_x, out_x, nullptr,
                                    nullptr, nullptr, 1024, 0);

    ln_kernel<<<4096, blk, 0, stream>>>(out_x, g3, be3, R0);
    for (int c = 0; c < 2; c++) {
        const bf16_t* Ac = R0 + (long)c * 2048 * 1024;
        bf16_t*       Hc = R1;
        float*        Xc = out_x + (long)c * 2048 * 1024;
        gemm_nt<<<gF1, blk, 0, stream>>>(Ac, 1024, 0, 0, W1, 0, 1024, 1024,
                                         b1, 0, nullptr, nullptr, Hc,
                                         nullptr, nullptr, 4096, 1);
        gemm_nt<<<gF2, blk, 0, stream>>>(Hc, 4096, 0, 0, W2, 0, 4096, 4096,
                                         b2, 0, Xc, Xc, nullptr,
                                         nullptr, nullptr, 1024, 0);
    }
}

// Round 7
// 1636.063 us; speedup vs baseline: 1.8081x; 1.4137x over previous
//
#include <hip/hip_runtime.h>

typedef __bf16 bf16_t;
typedef unsigned int u32;
typedef __attribute__((ext_vector_type(8))) __bf16 bf16x8;
typedef __attribute__((ext_vector_type(4))) __bf16 bf16x4;
typedef __attribute__((ext_vector_type(4))) float f32x4;

// B=4, S=SM=1024, D=1024, H=16, HD=64, DFF=4096; M = B*S = 4096 rows.
// Inputs fp32; d_out fp32 (x, sa_k, sa_v). Internals bf16 (MFMA).
// FAST PATH (ws >= 96MB, confirmed r6): bf16 weights cached in ws.

__device__ __forceinline__ bf16x8 load8f(const float* f) {
    float4 a = *(const float4*)f;
    float4 b = *(const float4*)(f + 4);
    bf16x8 r;
    r[0] = (bf16_t)a.x; r[1] = (bf16_t)a.y; r[2] = (bf16_t)a.z; r[3] = (bf16_t)a.w;
    r[4] = (bf16_t)b.x; r[5] = (bf16_t)b.y; r[6] = (bf16_t)b.z; r[7] = (bf16_t)b.w;
    return r;
}

// async 16B/lane global->LDS; LDS dest = wave-uniform base + lane*16
__device__ __forceinline__ void gll16(const void* g, const void* l) {
    __builtin_amdgcn_global_load_lds(
        (const __attribute__((address_space(1))) u32*)(unsigned long long)g,
        (__attribute__((address_space(3))) u32*)(unsigned int)(unsigned long long)l,
        16, 0, 0);
}

// ---------------------------------------------------------------------------
// fp32 -> bf16 weight/mem conversion (one contiguous buffer).
// [0,1M) Wq | [1M,2M) Wk | [2M,3M) Wv | [3M,4M) Wo | [4M,7M) mha_in_w |
// [7M,8M) mha_out_w | [8M,12M) W1 | [12M,16M) W2 | [16M,20M) mem
// ---------------------------------------------------------------------------
__global__ __launch_bounds__(256) void conv_kernel(
    const float* __restrict__ Wq, const float* __restrict__ Wk,
    const float* __restrict__ Wv, const float* __restrict__ Wo,
    const float* __restrict__ Wio, const float* __restrict__ Woo,
    const float* __restrict__ W1, const float* __restrict__ W2,
    const float* __restrict__ mem, bf16_t* __restrict__ dst)
{
    long e = ((long)blockIdx.x * 256 + threadIdx.x) * 8;
    const float* s; long o;
    if      (e <  1048576) { s = Wq;  o = e; }
    else if (e <  2097152) { s = Wk;  o = e -  1048576; }
    else if (e <  3145728) { s = Wv;  o = e -  2097152; }
    else if (e <  4194304) { s = Wo;  o = e -  3145728; }
    else if (e <  7340032) { s = Wio; o = e -  4194304; }
    else if (e <  8388608) { s = Woo; o = e -  7340032; }
    else if (e < 12582912) { s = W1;  o = e -  8388608; }
    else if (e < 16777216) { s = W2;  o = e - 12582912; }
    else                   { s = mem; o = e - 16777216; }
    *(bf16x8*)&dst[e] = load8f(s + o);
}

// ---------------------------------------------------------------------------
// LayerNorm: one block per fp32 row of 1024 -> bf16 out (fp32 math).
// ---------------------------------------------------------------------------
__global__ __launch_bounds__(256) void ln_kernel(
    const float* __restrict__ x,
    const float* __restrict__ g, const float* __restrict__ be,
    bf16_t* __restrict__ out)
{
    int row = blockIdx.x, t = threadIdx.x;
    float4 q = *(const float4*)(x + (long)row * 1024 + t * 4);
    float v[4] = {q.x, q.y, q.z, q.w};
    float s = v[0] + v[1] + v[2] + v[3];
    float s2 = v[0]*v[0] + v[1]*v[1] + v[2]*v[2] + v[3]*v[3];
    for (int off = 32; off > 0; off >>= 1) {
        s  += __shfl_down(s, off);
        s2 += __shfl_down(s2, off);
    }
    __shared__ float rs[4], rq[4];
    int w = t >> 6;
    if ((t & 63) == 0) { rs[w] = s; rq[w] = s2; }
    __syncthreads();
    s  = rs[0] + rs[1] + rs[2] + rs[3];
    s2 = rq[0] + rq[1] + rq[2] + rq[3];
    float mean = s * (1.0f / 1024.0f);
    float var  = s2 * (1.0f / 1024.0f) - mean * mean;
    float rstd = rsqrtf(var + 1e-5f);
    int c = t * 4;
    for (int i = 0; i < 4; i++)
        out[(long)row * 1024 + c + i] =
            (bf16_t)((v[i] - mean) * rstd * g[c + i] + be[c + i]);
}

// ---------------------------------------------------------------------------
// FAST NT GEMM v2: C = A * W^T (+bias,+relu,+fp32 resid)
// 128x128 tile, BK=64, double-buffered LDS (2x32KB), XOR-swizzled chunks,
// full-128B-row global_load_lds staging, column-major block remap (XCD-local
// A strips: lin%8 == mb%8 when gridDim.y % 8 == 0).
// mode 0: o0=f32 rm | o1=b16 rm | o2=b16 head
// mode 1 (QKV):     seg0->o0 b16 head, seg1->o1 f32 head, seg2->o2 f32 head
// mode 2 (crossKV): seg0->o0 b16 head, seg1->o1 b16 head
// ---------------------------------------------------------------------------
__global__ __launch_bounds__(256) void gemm_fast(
    const bf16_t* __restrict__ A, int lda, int a_head,
    const bf16_t* __restrict__ Wb, long w_off, int ldw, int K,
    const float* __restrict__ bias, long b_off,
    const float* resid,
    void* o0, void* o1, void* o2, int mode, int N, int do_relu)
{
    __shared__ __align__(16) bf16_t As[2][128 * 64];
    __shared__ __align__(16) bf16_t Bs[2][128 * 64];
    int tid = threadIdx.x;
    int lin = blockIdx.y * gridDim.x + blockIdx.x;   // HW dispatch order
    int mb = lin % gridDim.y, nb = lin / gridDim.y;  // m fastest -> A strip XCD-local
    int m0 = mb << 7, n0 = nb << 7;
    int w = tid >> 6, lane = tid & 63;
    int l15 = lane & 15, quad = lane >> 4;
    int wr = (w >> 1) << 6, wc = (w & 1) << 6;

    int srow = lane >> 3;                 // row within 8-row staging group
    int cgo  = ((lane & 7) ^ srow) << 3;  // swizzled source chunk offset (elems)

    f32x4 acc[4][4];
    for (int i = 0; i < 4; i++)
        for (int j = 0; j < 4; j++)
            acc[i][j] = (f32x4){0.f, 0.f, 0.f, 0.f};

    const bf16_t* Wg = Wb + w_off;
    int nk = K >> 6;

#define STAGE(P, KK)                                                          \
    {                                                                         \
        const bf16_t* Ab; long astr;                                          \
        if (a_head) {                                                         \
            int hh = (KK) >> 6;                                               \
            Ab = A + ((((long)(m0 >> 10)) * 16 + hh) * 1024 + (m0 & 1023)) * 64; \
            astr = 64;                                                        \
        } else {                                                              \
            Ab = A + (long)m0 * lda + (KK);                                   \
            astr = lda;                                                       \
        }                                                                     \
        const bf16_t* Bb = Wg + (long)n0 * ldw + (KK);                        \
        for (int t = 0; t < 4; t++) {                                         \
            int rb2 = (w << 5) + (t << 3);                                    \
            gll16(Ab + (long)(rb2 + srow) * astr + cgo, &As[P][rb2 << 6]);    \
            gll16(Bb + (long)(rb2 + srow) * ldw  + cgo, &Bs[P][rb2 << 6]);    \
        }                                                                     \
    }

#define COMPUTE(P)                                                            \
    for (int ks = 0; ks < 2; ks++) {                                          \
        bf16x8 af[4], bf_[4];                                                 \
        int gA = quad + (ks << 2);                                            \
        int sl = (gA ^ (l15 & 7)) << 3;                                       \
        for (int i = 0; i < 4; i++)                                           \
            af[i]  = *(const bf16x8*)&As[P][((wr + (i << 4) + l15) << 6) + sl]; \
        for (int j = 0; j < 4; j++)                                           \
            bf_[j] = *(const bf16x8*)&Bs[P][((wc + (j << 4) + l15) << 6) + sl]; \
        for (int i = 0; i < 4; i++)                                           \
            for (int j = 0; j < 4; j++)                                       \
                acc[i][j] = __builtin_amdgcn_mfma_f32_16x16x32_bf16(          \
                    af[i], bf_[j], acc[i][j], 0, 0, 0);                       \
    }

    STAGE(0, 0)
    __syncthreads();
    int p = 0;
    for (int kt = 0; kt < nk; kt++) {
        if (kt + 1 < nk) STAGE(p ^ 1, (kt + 1) << 6)
        COMPUTE(p)
        __syncthreads();
        p ^= 1;
    }
#undef STAGE
#undef COMPUTE

    int rb = quad << 2;  // C/D: col = lane&15, row = quad*4 + reg
    for (int i = 0; i < 4; i++) {
        for (int j = 0; j < 4; j++) {
            int col = n0 + wc + (j << 4) + l15;
            float bv = bias ? bias[b_off + col] : 0.0f;
            for (int r = 0; r < 4; r++) {
                int row = m0 + wr + (i << 4) + rb + r;
                float v = acc[i][j][r] + bv;
                if (do_relu) v = fmaxf(v, 0.0f);
                if (mode == 0) {
                    long idx = (long)row * N + col;
                    if (resid) v += resid[idx];
                    if (o0) ((float*)o0)[idx] = v;
                    if (o1) ((bf16_t*)o1)[idx] = (bf16_t)v;
                    if (o2) {
                        long hidx = (((long)(row >> 10) * 16 + (col >> 6)) * 1024
                                     + (row & 1023)) * 64 + (col & 63);
                        ((bf16_t*)o2)[hidx] = (bf16_t)v;
                    }
                } else {
                    int seg = col >> 10, c = col & 1023;
                    long hidx = (((long)(row >> 10) * 16 + (c >> 6)) * 1024
                                 + (row & 1023)) * 64 + (c & 63);
                    if (mode == 1) {
                        if (seg == 0)      ((bf16_t*)o0)[hidx] = (bf16_t)v;
                        else if (seg == 1) ((float*)o1)[hidx] = v;
                        else               ((float*)o2)[hidx] = v;
                    } else {
                        if (seg == 0)      ((bf16_t*)o0)[hidx] = (bf16_t)v;
                        else               ((bf16_t*)o1)[hidx] = (bf16_t)v;
                    }
                }
            }
        }
    }
}

// ---------------------------------------------------------------------------
// FALLBACK NT GEMM (round-5, fp32 weights) — only if ws < 96MB.
// ---------------------------------------------------------------------------
#define LDT 40

__global__ __launch_bounds__(256) void gemm_nt(
    const void* __restrict__ A, int lda, int a_head, int a_f32,
    const float* __restrict__ W, long w_off, int ldw,
    int K,
    const float* __restrict__ bias, long b_off,
    const float* resid,
    float*  out_f32, bf16_t* __restrict__ out_b16,
    float*  __restrict__ out_hf32, bf16_t* __restrict__ out_hb16,
    int N, int do_relu)
{
    __shared__ bf16_t As[128 * LDT];
    __shared__ bf16_t Bs[128 * LDT];
    int tid = threadIdx.x;
    int m0 = blockIdx.y << 7, n0 = blockIdx.x << 7;
    int wave = tid >> 6, lane = tid & 63;
    int wr = (wave >> 1) << 6;
    int wc = (wave & 1) << 6;
    int l15 = lane & 15, quad = lane >> 4;

    f32x4 acc[4][4];
    for (int i = 0; i < 4; i++)
        for (int j = 0; j < 4; j++)
            acc[i][j] = (f32x4){0.f, 0.f, 0.f, 0.f};

    int sr = tid >> 2;
    int sc = (tid & 3) << 3;

    for (int k0 = 0; k0 < K; k0 += 32) {
        int kk = k0 + sc;
        long ia0, ia1;
        if (a_head) {
            int hh = kk >> 6, dd = kk & 63;
            int r0g = m0 + sr, r1g = r0g + 64;
            ia0 = ((((long)(r0g >> 10) * 16 + hh) * 1024 + (r0g & 1023)) << 6) + dd;
            ia1 = ((((long)(r1g >> 10) * 16 + hh) * 1024 + (r1g & 1023)) << 6) + dd;
        } else {
            ia0 = (long)(m0 + sr) * lda + kk;
            ia1 = (long)(m0 + sr + 64) * lda + kk;
        }
        long iw0 = w_off + (long)(n0 + sr) * ldw + kk;
        long iw1 = w_off + (long)(n0 + sr + 64) * ldw + kk;
        __syncthreads();
        if (a_f32) {
            *(bf16x8*)&As[sr * LDT + sc]        = load8f((const float*)A + ia0);
            *(bf16x8*)&As[(sr + 64) * LDT + sc] = load8f((const float*)A + ia1);
        } else {
            *(bf16x8*)&As[sr * LDT + sc]        = *(const bf16x8*)((const bf16_t*)A + ia0);
            *(bf16x8*)&As[(sr + 64) * LDT + sc] = *(const bf16x8*)((const bf16_t*)A + ia1);
        }
        *(bf16x8*)&Bs[sr * LDT + sc]        = load8f(W + iw0);
        *(bf16x8*)&Bs[(sr + 64) * LDT + sc] = load8f(W + iw1);
        __syncthreads();
        bf16x8 afr[4], bfr[4];
        for (int i = 0; i < 4; i++)
            afr[i] = *(const bf16x8*)&As[(wr + i * 16 + l15) * LDT + quad * 8];
        for (int j = 0; j < 4; j++)
            bfr[j] = *(const bf16x8*)&Bs[(wc + j * 16 + l15) * LDT + quad * 8];
        for (int i = 0; i < 4; i++)
            for (int j = 0; j < 4; j++)
                acc[i][j] = __builtin_amdgcn_mfma_f32_16x16x32_bf16(
                    afr[i], bfr[j], acc[i][j], 0, 0, 0);
    }

    int rb = quad << 2;
    for (int i = 0; i < 4; i++) {
        for (int j = 0; j < 4; j++) {
            int col = n0 + wc + (j << 4) + l15;
            float bv = bias ? bias[b_off + col] : 0.0f;
            for (int r = 0; r < 4; r++) {
                int row = m0 + wr + (i << 4) + rb + r;
                float v = acc[i][j][r] + bv;
                if (do_relu) v = fmaxf(v, 0.0f);
                long idx = (long)row * N + col;
                if (resid) v += resid[idx];
                if (out_f32) out_f32[idx] = v;
                if (out_b16) out_b16[idx] = (bf16_t)v;
                if (out_hf32 || out_hb16) {
                    int bb = row >> 10, ss = row & 1023, hh = col >> 6, dd = col & 63;
                    long hidx = (((long)bb * 16 + hh) * 1024 + ss) * 64 + dd;
                    if (out_hf32) out_hf32[hidx] = v;
                    if (out_hb16) out_hb16[hidx] = (bf16_t)v;
                }
            }
        }
    }
}

// ---------------------------------------------------------------------------
// Flash attention (fp32 VALU, online softmax). Q bf16 head [B*H,S,64];
// K/V head layout, bf16 or fp32 per kv_f32. Output bf16 in-place over Q.
// ---------------------------------------------------------------------------
__global__ __launch_bounds__(256) void attn_kernel(
    const bf16_t* Q, const void* __restrict__ K,
    const void* __restrict__ V, bf16_t* AO,
    int Sk, int causal, int kv_f32)
{
    __shared__ float  Qs[64][68];
    __shared__ float  Ks[64][68];
    __shared__ float  Vs[64][68];
    __shared__ bf16_t Ps[64][72];
    int tid = threadIdx.x;
    int qt = blockIdx.x, bh = blockIdx.y;

    const bf16_t* Qb = Q + ((long)bh * 1024 + qt * 64) * 64;
    for (int c = tid; c < 512; c += 256) {
        int r = c >> 3, c8 = (c & 7) << 3;
        bf16x8 qv = *(const bf16x8*)&Qb[r * 64 + c8];
        for (int i = 0; i < 8; i++) Qs[r][c8 + i] = (float)qv[i] * 0.125f;
    }

    int r0 = (tid >> 4) << 2;
    int c0 = (tid & 15) << 2;
    float m_i[4] = {-1e30f, -1e30f, -1e30f, -1e30f};
    float l_i[4] = {0.f, 0.f, 0.f, 0.f};
    float o[4][4] = {};
    int nt = causal ? (qt + 1) : (Sk >> 6);
    long kvbase = (long)bh * Sk * 64;

    for (int kt = 0; kt < nt; kt++) {
        __syncthreads();
        int kbase = kt << 6;
        for (int c = tid; c < 512; c += 256) {
            int r = c >> 3, c8 = (c & 7) << 3;
            long off = kvbase + (long)(kbase + r) * 64 + c8;
            if (kv_f32) {
                const float* kp = (const float*)K + off;
                const float* vp = (const float*)V + off;
                float4 ka = *(const float4*)kp, kb = *(const float4*)(kp + 4);
                float4 va = *(const float4*)vp, vb = *(const float4*)(vp + 4);
                Ks[r][c8+0]=ka.x; Ks[r][c8+1]=ka.y; Ks[r][c8+2]=ka.z; Ks[r][c8+3]=ka.w;
                Ks[r][c8+4]=kb.x; Ks[r][c8+5]=kb.y; Ks[r][c8+6]=kb.z; Ks[r][c8+7]=kb.w;
                Vs[r][c8+0]=va.x; Vs[r][c8+1]=va.y; Vs[r][c8+2]=va.z; Vs[r][c8+3]=va.w;
                Vs[r][c8+4]=vb.x; Vs[r][c8+5]=vb.y; Vs[r][c8+6]=vb.z; Vs[r][c8+7]=vb.w;
            } else {
                bf16x8 kv = *(const bf16x8*)((const bf16_t*)K + off);
                bf16x8 vv = *(const bf16x8*)((const bf16_t*)V + off);
                for (int i = 0; i < 8; i++) {
                    Ks[r][c8 + i] = (float)kv[i];
                    Vs[r][c8 + i] = (float)vv[i];
                }
            }
        }
        __syncthreads();

        float s[4][4] = {};
        for (int d = 0; d < 64; d += 4) {
            float4 kc[4];
            for (int j = 0; j < 4; j++) kc[j] = *(const float4*)&Ks[c0 + j][d];
            for (int i = 0; i < 4; i++) {
                float4 qv = *(const float4*)&Qs[r0 + i][d];
                for (int j = 0; j < 4; j++)
                    s[i][j] += qv.x * kc[j].x + qv.y * kc[j].y +
                               qv.z * kc[j].z + qv.w * kc[j].w;
            }
        }
        if (causal) {
            int qrow = (qt << 6) + r0;
            for (int i = 0; i < 4; i++)
                for (int j = 0; j < 4; j++)
                    if (kbase + c0 + j > qrow + i) s[i][j] = -1e30f;
        }
        for (int i = 0; i < 4; i++) {
            float mx = fmaxf(fmaxf(s[i][0], s[i][1]), fmaxf(s[i][2], s[i][3]));
            for (int off = 1; off < 16; off <<= 1) mx = fmaxf(mx, __shfl_xor(mx, off));
            float mnew = fmaxf(m_i[i], mx);
            float alpha = __expf(m_i[i] - mnew);
            float p[4], rsum = 0.f;
            for (int j = 0; j < 4; j++) { p[j] = __expf(s[i][j] - mnew); rsum += p[j]; }
            for (int off = 1; off < 16; off <<= 1) rsum += __shfl_xor(rsum, off);
            l_i[i] = l_i[i] * alpha + rsum;
            m_i[i] = mnew;
            for (int j = 0; j < 4; j++) {
                o[i][j] *= alpha;
                Ps[r0 + i][c0 + j] = (bf16_t)p[j];
            }
        }
        __syncthreads();
        for (int kk = 0; kk < 64; kk += 4) {
            bf16x4 pr[4];
            for (int i = 0; i < 4; i++) pr[i] = *(const bf16x4*)&Ps[r0 + i][kk];
            for (int x = 0; x < 4; x++) {
                float4 vv = *(const float4*)&Vs[kk + x][c0];
                for (int i = 0; i < 4; i++) {
                    float pv = (float)pr[i][x];
                    o[i][0] += pv * vv.x; o[i][1] += pv * vv.y;
                    o[i][2] += pv * vv.z; o[i][3] += pv * vv.w;
                }
            }
        }
    }

    bf16_t* Ob = AO + ((long)bh * 1024 + qt * 64) * 64;
    for (int i = 0; i < 4; i++) {
        float inv = 1.0f / l_i[i];
        for (int j = 0; j < 4; j++)
            Ob[(r0 + i) * 64 + c0 + j] = (bf16_t)(o[i][j] * inv);
    }
}

// ---------------------------------------------------------------------------
extern "C" void kernel_launch(void* const* d_in, const int* in_sizes, int n_in,
                              void* d_out, int out_size, void* d_ws, size_t ws_size,
                              hipStream_t stream)
{
    (void)in_sizes; (void)n_in; (void)out_size;
    const float* tgt       = (const float*)d_in[0];
    const float* mem       = (const float*)d_in[1];
    const float* Wq        = (const float*)d_in[2];
    const float* Wk        = (const float*)d_in[3];
    const float* Wv        = (const float*)d_in[4];
    const float* Wo        = (const float*)d_in[5];
    const float* mha_in_w  = (const float*)d_in[6];
    const float* mha_in_b  = (const float*)d_in[7];
    const float* mha_out_w = (const float*)d_in[8];
    const float* mha_out_b = (const float*)d_in[9];
    const float* W1        = (const float*)d_in[10];
    const float* b1        = (const float*)d_in[11];
    const float* W2        = (const float*)d_in[12];
    const float* b2        = (const float*)d_in[13];
    const float* g1        = (const float*)d_in[14];
    const float* be1       = (const float*)d_in[15];
    const float* g2        = (const float*)d_in[16];
    const float* be2       = (const float*)d_in[17];
    const float* g3        = (const float*)d_in[18];
    const float* be3       = (const float*)d_in[19];

    float* out_x = (float*)d_out;
    float* out_k = out_x + (1 << 22);
    float* out_v = out_k + (1 << 22);

    bf16_t* R0 = (bf16_t*)d_ws;
    bf16_t* R1 = R0 + (1 << 22);
    bf16_t* R2 = R1 + (1 << 22);

    dim3 blk(256);
    dim3 gA(16, 64);

    if (ws_size >= ((size_t)96 << 20)) {
        // ---------------- FAST PATH ----------------
        bf16_t* Hff  = R2 + (1 << 22);                              // [24,56) MB
        bf16_t* Wb   = (bf16_t*)((char*)d_ws + ((size_t)56 << 20)); // [56,88)
        bf16_t* memb = Wb + 16777216;                               // [88,96)
        const long WO_OFF  = 3145728;
        const long CQ_OFF  = 4194304;
        const long CKV_OFF = 5242880;
        const long CO_OFF  = 7340032;
        const long W1_OFF  = 8388608;
        const long W2_OFF  = 12582912;

        conv_kernel<<<10240, blk, 0, stream>>>(Wq, Wk, Wv, Wo, mha_in_w,
                                               mha_out_w, W1, W2, mem, Wb);

        // ---- self-attention ----
        ln_kernel<<<4096, blk, 0, stream>>>(tgt, g1, be1, R0);
        gemm_fast<<<dim3(24, 32), blk, 0, stream>>>(R0, 1024, 0, Wb, 0, 1024, 1024,
                                                    nullptr, 0, nullptr,
                                                    R1, out_k, out_v, 1, 3072, 0);
        attn_kernel<<<gA, blk, 0, stream>>>(R1, out_k, out_v, R1, 1024, 1, 1);
        gemm_fast<<<dim3(8, 32), blk, 0, stream>>>(R1, 0, 1, Wb, WO_OFF, 1024, 1024,
                                                   nullptr, 0, tgt,
                                                   out_x, nullptr, nullptr, 0, 1024, 0);

        // ---- cross-attention ----
        ln_kernel<<<4096, blk, 0, stream>>>(out_x, g2, be2, R0);
        gemm_fast<<<dim3(8, 32), blk, 0, stream>>>(R0, 1024, 0, Wb, CQ_OFF, 1024, 1024,
                                                   mha_in_b, 0, nullptr,
                                                   nullptr, nullptr, R1, 0, 1024, 0);
        gemm_fast<<<dim3(16, 32), blk, 0, stream>>>(memb, 1024, 0, Wb, CKV_OFF, 1024, 1024,
                                                    mha_in_b, 1024, nullptr,
                                                    R2, R0, nullptr, 2, 2048, 0);
        attn_kernel<<<gA, blk, 0, stream>>>(R1, R2, R0, R1, 1024, 0, 0);
        gemm_fast<<<dim3(8, 32), blk, 0, stream>>>(R1, 0, 1, Wb, CO_OFF, 1024, 1024,
                                                   mha_out_b, 0, out_x,
                                                   out_x, nullptr, nullptr, 0, 1024, 0);

        // ---- FFN ----
        ln_kernel<<<4096, blk, 0, stream>>>(out_x, g3, be3, R0);
        gemm_fast<<<dim3(32, 32), blk, 0, stream>>>(R0, 1024, 0, Wb, W1_OFF, 1024, 1024,
                                                    b1, 0, nullptr,
                                                    nullptr, Hff, nullptr, 0, 4096, 1);
        gemm_fast<<<dim3(8, 32), blk, 0, stream>>>(Hff, 4096, 0, Wb, W2_OFF, 4096, 4096,
                                                   b2, 0, out_x,
                                                   out_x, nullptr, nullptr, 0, 1024, 0);
        return;
    }

    // ---------------- FALLBACK (round-5, known passing) ----------------
    dim3 gD(8, 32);
    dim3 gF1(32, 16);
    dim3 gF2(8, 16);

    ln_kernel<<<4096, blk, 0, stream>>>(tgt, g1, be1, R0);
    gemm_nt<<<gD, blk, 0, stream>>>(R0, 1024, 0, 0, Wq, 0, 1024, 1024,
                                    nullptr, 0, nullptr, nullptr, nullptr,
                                    nullptr, R1, 1024, 0);
    gemm_nt<<<gD, blk, 0, stream>>>(R0, 1024, 0, 0, Wk, 0, 1024, 1024,
                                    nullptr, 0, nullptr, nullptr, nullptr,
                                    out_k, nullptr, 1024, 0);
    gemm_nt<<<gD, blk, 0, stream>>>(R0, 1024, 0, 0, Wv, 0, 1024, 1024,
                                    nullptr, 0, nullptr, nullptr, nullptr,
                                    out_v, nullptr, 1024, 0);
    attn_kernel<<<gA, blk, 0, stream>>>(R1, out_k, out_v, R1, 1024, 1, 1);
    gemm_nt<<<gD, blk, 0, stream>>>(R1, 0, 1, 0, Wo, 0, 1024, 1024,
                                    nullptr, 0, tgt, out_x, nullptr,
                                    nullptr, nullptr, 1024, 0);

    ln_kernel<<<4096, blk, 0, stream>>>(out_x, g2, be2, R0);
    gemm_nt<<<gD, blk, 0, stream>>>(R0, 1024, 0, 0, mha_in_w, 0, 1024, 1024,
                                    mha_in_b, 0, nullptr, nullptr, nullptr,
                                    nullptr, R1, 1024, 0);
    gemm_nt<<<gD, blk, 0, stream>>>(mem, 1024, 0, 1, mha_in_w, (long)1 << 20, 1024, 1024,
                                    mha_in_b, 1024, nullptr, nullptr, nullptr,
                                    nullptr, R2, 1024, 0);
    gemm_nt<<<gD, blk, 0, stream>>>(mem, 1024, 0, 1, mha_in_w, (long)2 << 20, 1024, 1024,
                                    mha_in_b, 2048, nullptr, nullptr, nullptr,
                                    nullptr, R0, 1024, 0);
    attn_kernel<<<gA, blk, 0, stream>>>(R1, R2, R0, R1, 1024, 0, 0);
    gemm_nt<<<gD, blk, 0, stream>>>(R1, 0, 1, 0, mha_out_w, 0, 1024, 1024,
                                    mha_out_b, 0, out_x, out_x, nullptr,
                                    nullptr, nullptr, 1024, 0);

    ln_kernel<<<4096, blk, 0, stream>>>(out_x, g3, be3, R0);
    for (int c = 0; c < 2; c++) {
        const bf16_t* Ac = R0 + (long)c * 2048 * 1024;
        bf16_t*       Hc = R1;
        float*        Xc = out_x + (long)c * 2048 * 1024;
        gemm_nt<<<gF1, blk, 0, stream>>>(Ac, 1024, 0, 0, W1, 0, 1024, 1024,
                                         b1, 0, nullptr, nullptr, Hc,
                                         nullptr, nullptr, 4096, 1);
        gemm_nt<<<gF2, blk, 0, stream>>>(Hc, 4096, 0, 0, W2, 0, 4096, 4096,
                                         b2, 0, Xc, Xc, nullptr,
                                         nullptr, nullptr, 1024, 0);
    }
}